// Round 1
// baseline (379.139 us; speedup 1.0000x reference)
//
#include <hip/hip_runtime.h>
#include <hip/hip_fp16.h>

#define C 4096
#define NN 110
#define MPAD 112
#define BN 128
#define BK 64
#define KCHUNK 512
#define LDSTR 72   // half-elem stride (64 + 8 pad) keeps 16B alignment for b128

typedef _Float16 f16x8 __attribute__((ext_vector_type(8)));
typedef float fx4 __attribute__((ext_vector_type(4)));

// ---------------------------------------------------------------------------
// prep1: A1[112][4096] = fp16(x), rows >=110 zeroed
// ---------------------------------------------------------------------------
__global__ void prep1_kernel(const float* __restrict__ x, _Float16* __restrict__ A1) {
    int idx = blockIdx.x * 256 + threadIdx.x;          // 0 .. 112*4096-1
    int n = idx >> 12;
    float v = (n < NN) ? x[idx] : 0.f;
    A1[idx] = (_Float16)v;
}

// ---------------------------------------------------------------------------
// mm: Cacc[0:110, 0:4096] += A16[0:112, k0:k0+512] @ fp16(B[k0:k0+512, 0:4096])
// A16 fp16 row-major (lda = Ktot), B fp32 row-major [Ktot][4096], atomicAdd out.
// Block: 256 thr = 4 waves, tile 112(m) x 128(n), wave w -> cols w*32..w*32+31.
// ---------------------------------------------------------------------------
__global__ __launch_bounds__(256, 2)
void mm_kernel(const _Float16* __restrict__ A, const float* __restrict__ B,
               float* __restrict__ Cacc, int lda) {
    __shared__ _Float16 As[MPAD * LDSTR];   // [112][72]
    __shared__ _Float16 Bs[BN * LDSTR];     // transposed: Bs[n][k], [128][72]

    const int t  = threadIdx.x;
    const int j0 = blockIdx.x * BN;
    const int k0 = blockIdx.y * KCHUNK;
    const int w   = t >> 6;
    const int L   = t & 63;
    const int l15 = L & 15;
    const int q   = L >> 4;       // quad 0..3

    const int bc  = t & 127;      // staging column 0..127
    const int bgq = t >> 7;       // 0..1

    fx4 acc[7][2];
    #pragma unroll
    for (int mt = 0; mt < 7; ++mt)
        #pragma unroll
        for (int nt = 0; nt < 2; ++nt)
            acc[mt][nt] = (fx4){0.f, 0.f, 0.f, 0.f};

    for (int kc = 0; kc < KCHUNK; kc += BK) {
        // ---- stage A chunk [112][64] fp16 via b128
        {
            int idx = t;
            #pragma unroll
            for (int i = 0; i < 4; ++i) {
                if (idx < MPAD * (BK / 8)) {          // 896
                    int row = idx >> 3;
                    int ko  = (idx & 7) << 3;
                    *(f16x8*)(As + row * LDSTR + ko) =
                        *(const f16x8*)(A + (size_t)row * lda + k0 + kc + ko);
                }
                idx += 256;
            }
        }
        // ---- stage B chunk [64][128] fp32 -> fp16, transposed into Bs[n][k]
        {
            #pragma unroll
            for (int p = 0; p < 16; ++p) {
                int r = (bgq * 16 + p) * 2;           // rows r, r+1
                float v0 = B[(size_t)(k0 + kc + r) * C + j0 + bc];
                float v1 = B[(size_t)(k0 + kc + r + 1) * C + j0 + bc];
                union { _Float16 h[2]; unsigned u; } pk;
                pk.h[0] = (_Float16)v0;
                pk.h[1] = (_Float16)v1;
                *(unsigned*)(Bs + bc * LDSTR + r) = pk.u;
            }
        }
        __syncthreads();
        // ---- MFMA: 2 k-steps of 32, 7 m-tiles x 2 n-tiles per wave
        #pragma unroll
        for (int s = 0; s < 2; ++s) {
            const int ko = s * 32 + q * 8;
            f16x8 bfrag[2];
            #pragma unroll
            for (int nt = 0; nt < 2; ++nt)
                bfrag[nt] = *(const f16x8*)(Bs + (w * 32 + nt * 16 + l15) * LDSTR + ko);
            #pragma unroll
            for (int mt = 0; mt < 7; ++mt) {
                f16x8 afrag = *(const f16x8*)(As + (mt * 16 + l15) * LDSTR + ko);
                #pragma unroll
                for (int nt = 0; nt < 2; ++nt)
                    acc[mt][nt] = __builtin_amdgcn_mfma_f32_16x16x32_f16(
                        afrag, bfrag[nt], acc[mt][nt], 0, 0, 0);
            }
        }
        __syncthreads();
    }

    // ---- epilogue: fp32 atomic accumulate (C/D layout: col=lane&15, row=q*4+reg)
    #pragma unroll
    for (int mt = 0; mt < 7; ++mt) {
        #pragma unroll
        for (int nt = 0; nt < 2; ++nt) {
            const int col = j0 + w * 32 + nt * 16 + l15;
            #pragma unroll
            for (int r = 0; r < 4; ++r) {
                int row = mt * 16 + q * 4 + r;
                if (row < NN)
                    atomicAdd(&Cacc[(size_t)row * C + col], acc[mt][nt][r]);
            }
        }
    }
}

// ---------------------------------------------------------------------------
// agg: per 16-col tile, builds A3 = fp16([h+b2, aggr]) [112][8192]
// aggr[j,c] = sum_i mask[i,j]*(h[i,c]+b2[c]) / max(deg_j,1)
// ---------------------------------------------------------------------------
__global__ __launch_bounds__(256)
void agg_kernel(const float* __restrict__ h_raw, const int* __restrict__ adj,
                const float* __restrict__ b2, _Float16* __restrict__ A3) {
    __shared__ float hb[NN * 16];
    __shared__ unsigned long long mlo[NN], mhi[NN];
    __shared__ float degs[NN];
    const int t  = threadIdx.x;
    const int c0 = blockIdx.x * 16;

    // load h tile (+bias), emit A3 first half
    for (int idx = t; idx < NN * 16; idx += 256) {
        int n = idx >> 4, c = idx & 15;
        float v = h_raw[(size_t)n * C + c0 + c] + b2[c0 + c];
        hb[idx] = v;
        A3[(size_t)n * (2 * C) + c0 + c] = (_Float16)v;
    }
    // zero pad rows 110,111 (both halves of this c-tile)
    if (t < 64) {
        int n  = NN + (t >> 5);
        int hs = (t >> 4) & 1;
        int c  = t & 15;
        A3[(size_t)n * (2 * C) + hs * C + c0 + c] = (_Float16)0.f;
    }
    // mask bits + degree per target j
    if (t < NN) {
        int j = t;
        unsigned long long lo = 0, hi = 0;
        int dg = 0;
        for (int i = 0; i < 64; ++i) {
            int m = (adj[i * NN + j] != 0);
            lo |= ((unsigned long long)m) << i; dg += m;
        }
        for (int i = 64; i < NN; ++i) {
            int m = (adj[i * NN + j] != 0);
            hi |= ((unsigned long long)m) << (i - 64); dg += m;
        }
        mlo[j] = lo; mhi[j] = hi;
        degs[j] = (float)(dg > 0 ? dg : 1);
    }
    __syncthreads();
    // aggr -> A3 second half
    for (int idx = t; idx < NN * 16; idx += 256) {
        int j = idx >> 4, c = idx & 15;
        unsigned long long lo = mlo[j], hi = mhi[j];
        float a = 0.f;
        for (int i = 0; i < 64; ++i)
            if ((lo >> i) & 1) a += hb[i * 16 + c];
        for (int i = 64; i < NN; ++i)
            if ((hi >> (i - 64)) & 1) a += hb[i * 16 + c];
        A3[(size_t)j * (2 * C) + C + c0 + c] = (_Float16)(a / degs[j]);
    }
}

// ---------------------------------------------------------------------------
// fin: out[j,c] = sum_k Wl[j,k] * relu(z_raw[k,c]+b1[c]) + bl[j]
// grid (64 c-tiles, 28 j-groups of 4); Wl loads are wave-uniform (scalar).
// ---------------------------------------------------------------------------
__global__ __launch_bounds__(256)
void fin_kernel(const float* __restrict__ z_raw, const float* __restrict__ b1,
                const float* __restrict__ Wl, const float* __restrict__ bl,
                float* __restrict__ out) {
    __shared__ float zs[NN * 64];
    const int t  = threadIdx.x;
    const int c0 = blockIdx.x * 64;
    const int j  = blockIdx.y * 4 + (t >> 6);
    const int c  = t & 63;

    for (int idx = t; idx < NN * 64; idx += 256) {
        int k = idx >> 6, cc = idx & 63;
        float v = z_raw[(size_t)k * C + c0 + cc] + b1[c0 + cc];
        zs[idx] = fmaxf(v, 0.f);
    }
    __syncthreads();
    if (j < NN) {
        float a = bl[j];
        #pragma unroll 2
        for (int k = 0; k < NN; ++k)
            a += Wl[j * NN + k] * zs[k * 64 + c];
        out[(size_t)j * C + c0 + c] = a;
    }
}

// ---------------------------------------------------------------------------
extern "C" void kernel_launch(void* const* d_in, const int* in_sizes, int n_in,
                              void* d_out, int out_size, void* d_ws, size_t ws_size,
                              hipStream_t stream) {
    const float* x   = (const float*)d_in[0];
    const int*   adj = (const int*)d_in[1];
    const float* W2  = (const float*)d_in[2];
    const float* b2  = (const float*)d_in[3];
    const float* W1  = (const float*)d_in[4];
    const float* b1  = (const float*)d_in[5];
    const float* Wl  = (const float*)d_in[6];
    const float* bl  = (const float*)d_in[7];
    float* out = (float*)d_out;

    char* ws = (char*)d_ws;
    float*    h_raw = (float*)(ws);                    // 110*4096 f32
    float*    z_raw = (float*)(ws + 1802240);          // 110*4096 f32
    _Float16* A1    = (_Float16*)(ws + 3604480);       // 112*4096 f16
    _Float16* A3    = (_Float16*)(ws + 4521984);       // 112*8192 f16

    hipMemsetAsync(d_ws, 0, 3604480, stream);                           // zero h_raw,z_raw
    prep1_kernel<<<(MPAD * C) / 256, 256, 0, stream>>>(x, A1);
    mm_kernel<<<dim3(C / BN, C / KCHUNK), 256, 0, stream>>>(A1, W2, h_raw, C);
    agg_kernel<<<C / 16, 256, 0, stream>>>(h_raw, adj, b2, A3);
    mm_kernel<<<dim3(C / BN, (2 * C) / KCHUNK), 256, 0, stream>>>(A3, W1, z_raw, 2 * C);
    fin_kernel<<<dim3(C / 64, 28), 256, 0, stream>>>(z_raw, b1, Wl, bl, out);
}